// Round 8
// baseline (271.780 us; speedup 1.0000x reference)
//
#include <hip/hip_runtime.h>
#include <hip/hip_bf16.h>

typedef __attribute__((ext_vector_type(4))) float f32x4;
typedef __attribute__((ext_vector_type(8))) short s16x8;

static __device__ __forceinline__ short f2bf(float x) {
  __hip_bfloat16 h = __float2bfloat16(x);
  return *reinterpret_cast<short*>(&h);
}

// Intra-wave LDS fence: wait own wave's DS ops; sched_barrier stops hoisting (rule #18).
static __device__ __forceinline__ void wave_lgkm0() {
  asm volatile("s_waitcnt lgkmcnt(0)" ::: "memory");
  __builtin_amdgcn_sched_barrier(0);
}

// ---------------- MFMA MPS stages 1..3, two-phase bulk-C' structure ----------------
// Per phase: cooperatively build C' for up to 10 sites into LDS (deeply pipelined
// coalesced loads), one barrier, then all 4 waves run the 10-site chain BARRIER-FREE:
// v lives in registers (MFMA C-operand, D-layout); the D->A relayout goes through
// vls with intra-wave lgkm fences only (R4-proven math, absmax 1.5).
// Barriers per stage: 1 + 2*ceil(S/10) (was 1 + S).
// CS k'-columns i>=20 of each 32-block are zeroed once and never written; the A-frag
// is 0 there (vls cols 20..35 = 0), so 0*0 contributes nothing and no NaN can enter.
template<int STAGE>
__global__ __launch_bounds__(256)
void k_mps(const float* __restrict__ xsrc, const float* __restrict__ ysrc,
           const float* __restrict__ cores, const float* __restrict__ alpha,
           const float* __restrict__ label, const float* __restrict__ omega,
           const float* __restrict__ gam, const float* __restrict__ bet,
           float* __restrict__ yout) {
  constexpr int S  = (STAGE == 1) ? 3 : 20;
  constexpr int PH = (S < 10) ? S : 10;

  extern __shared__ __align__(16) char smem[];
  float (*u4)[64][4] = (float (*)[64][4])smem;                       // S*1024 B
  float (*vls)[36]   = (float (*)[36])(smem + S * 1024);             // 9216 B
  float* Lw_l        = (float*)(smem + S * 1024 + 9216);             // 1600 B
  float* redA        = Lw_l + 400;                                   // 4
  float* redB        = redA + 4;                                     // 4
  float* stats       = redB + 4;                                     // 2 (+pad to 48)
  short (*CS)[20][168] = (short (*)[20][168])(smem + S * 1024 + 9216 + 1600 + 48);

  const int p = blockIdx.x, t = threadIdx.x;
  const int b = t & 63, q = t >> 6;
  const int m = b & 15, quad = b >> 4;
  const int bl = q * 16 + m;
  const int mrow1 = (m < 4) ? m + 16 : m;   // clamped B-row for acc1 (junk lanes discarded)

  const float* cbase = cores + (size_t)p * S * 3200;

  // ---- Lw[o][j] = sum_k label[o][j][k]*omega[k] ----
  for (int e = t; e < 400; e += 256) {
    int o = e / 20, j = e % 20;
    float a = 0.f;
#pragma unroll
    for (int k = 0; k < 20; ++k) a = fmaf(label[o * 400 + j * 20 + k], omega[k], a);
    Lw_l[e] = a;
  }

  // ---- zero FULL CS (cols i>=20 of each 32-block are never written later);
  //      init vls = alpha (cols 20..35 zero) ----
  {
    int* cz = (int*)&CS[0][0][0];                    // PH*20*168 shorts
    for (int i = t; i < PH * 1680; i += 256) cz[i] = 0;
    for (int i = t; i < 64 * 36; i += 256) {
      int col = i % 36;
      vls[i / 36][col] = (col < 20) ? alpha[col] : 0.f;
    }
  }

  // ---- v in registers, MFMA D-layout ----
  float vr0[4], vr1[4];
  {
    float a0 = alpha[m];
    float a1 = (m < 4) ? alpha[m + 16] : 0.f;
#pragma unroll
    for (int r = 0; r < 4; ++r) { vr0[r] = a0; vr1[r] = a1; }
  }

  // ---- gather u (faithful raw-reshape unfold permutation); u4[k][b][g=q] ----
  for (int k = 0; k < S; ++k) {
    float val;
    if (STAGE == 1) {
      int L = q * 3072 + p * 3 + k;           // [4,1024,3] flat
      int c = L >> 12, r = L & 4095;          // dims [3,32,32,2,2]
      int hh = 2 * (r >> 7) + ((r >> 1) & 1);
      int ww = 2 * ((r >> 2) & 31) + (r & 1);
      val = xsrc[(b * 3 + c) * 4096 + hh * 64 + ww];
    } else if (STAGE == 2) {
      int L = q * 5120 + p * 20 + k;          // [4,256,20] flat
      int c = L >> 10, r = L & 1023;          // dims [20,16,16,2,2]
      int f = c * 1024 + (2 * (r >> 6) + ((r >> 1) & 1)) * 32
                        + (2 * ((r >> 2) & 15) + (r & 1));
      val = ysrc[f * 64 + b];                 // b innermost -> coalesced
    } else {
      int L = q * 1280 + p * 20 + k;          // [4,64,20] flat
      int c = L >> 8, r = L & 255;            // dims [20,8,8,2,2]
      int f = c * 256 + (2 * (r >> 5) + ((r >> 1) & 1)) * 16
                       + (2 * ((r >> 2) & 7) + (r & 1));
      val = ysrc[f * 64 + b];
    }
    u4[k][b][q] = val;
  }
  __syncthreads();

  // ---- phased: bulk C' build (cooperative), then barrier-free chain ----
  for (int ph = 0; ph < S; ph += PH) {
    const int ns = (S - ph < PH) ? (S - ph) : PH;

    // build C' for sites ph..ph+ns-1 (each of the 8 loads coalesced over lanes)
#pragma unroll 4
    for (int uidx = t; uidx < ns * 400; uidx += 256) {
      const int ls = uidx / 400, e = uidx - ls * 400;
      const float* cs = cbase + (size_t)(ph + ls) * 3200;
      float r0 = cs[e],        r1 = cs[400 + e],  r2 = cs[800 + e],  r3 = cs[1200 + e];
      float r4 = cs[1600 + e], r5 = cs[2000 + e], r6 = cs[2400 + e], r7 = cs[2800 + e];
      const int i = e / 20, j = e - i * 20;
      short* row = &CS[ls][j][0];
      row[i]       = f2bf(r0 - r4);
      row[32 + i]  = f2bf(r1 - r5);
      row[64 + i]  = f2bf(r2 - r6);
      row[96 + i]  = f2bf(r3 - r7);
      float csum = r4 + r5 + r6 + r7;
      if (i == j) csum -= 1.f;
      row[128 + i] = f2bf(csum);
    }
    __syncthreads();

    // barrier-free chain over ns sites (wave-autonomous)
    for (int ls = 0; ls < ns; ++ls) {
      const int s = ph + ls;
      const float4 uu4 = *(const float4*)&u4[s][bl][0];
      const float4 va4 = *(const float4*)&vls[bl][quad * 8];
      const float4 vb4 = *(const float4*)&vls[bl][quad * 8 + 4];
      const float vv[8] = {va4.x, va4.y, va4.z, va4.w, vb4.x, vb4.y, vb4.z, vb4.w};
      const float um[5] = {uu4.x, uu4.y, uu4.z, uu4.w, 1.f};

      f32x4 acc0, acc1;
#pragma unroll
      for (int r = 0; r < 4; ++r) { acc0[r] = vr0[r]; acc1[r] = vr1[r]; }
#pragma unroll
      for (int kt = 0; kt < 5; ++kt) {
        s16x8 aF;
#pragma unroll
        for (int j2 = 0; j2 < 8; ++j2) aF[j2] = f2bf(vv[j2] * um[kt]);
        const s16x8 bF0 = *(const s16x8*)&CS[ls][m][kt * 32 + quad * 8];
        const s16x8 bF1 = *(const s16x8*)&CS[ls][mrow1][kt * 32 + quad * 8];
        acc0 = __builtin_amdgcn_mfma_f32_16x16x32_bf16(aF, bF0, acc0, 0, 0, 0);
        acc1 = __builtin_amdgcn_mfma_f32_16x16x32_bf16(aF, bF1, acc1, 0, 0, 0);
      }
#pragma unroll
      for (int r = 0; r < 4; ++r) { vr0[r] = acc0[r]; vr1[r] = acc1[r]; }
      // publish D->A relayout for next site (intra-wave only)
#pragma unroll
      for (int r = 0; r < 4; ++r) vls[q * 16 + quad * 4 + r][m] = acc0[r];
      if (m < 4) {
#pragma unroll
        for (int r = 0; r < 4; ++r) vls[q * 16 + quad * 4 + r][m + 16] = acc1[r];
      }
      wave_lgkm0();
    }
    __syncthreads();   // chain done -> CS may be rebuilt / epilogue may read vls
  }

  // ---- epilogue: Lw projection + fused BatchNorm (stats over 64b x 20o) ----
  float vf[20];
  {
    const float4 v0 = *(const float4*)&vls[b][0];
    const float4 v1 = *(const float4*)&vls[b][4];
    const float4 v2 = *(const float4*)&vls[b][8];
    const float4 v3 = *(const float4*)&vls[b][12];
    const float4 v4 = *(const float4*)&vls[b][16];
    vf[0]=v0.x; vf[1]=v0.y; vf[2]=v0.z; vf[3]=v0.w;
    vf[4]=v1.x; vf[5]=v1.y; vf[6]=v1.z; vf[7]=v1.w;
    vf[8]=v2.x; vf[9]=v2.y; vf[10]=v2.z; vf[11]=v2.w;
    vf[12]=v3.x; vf[13]=v3.y; vf[14]=v3.z; vf[15]=v3.w;
    vf[16]=v4.x; vf[17]=v4.y; vf[18]=v4.z; vf[19]=v4.w;
  }
  float yo[5];
  float s1 = 0.f, s2 = 0.f;
#pragma unroll
  for (int jj = 0; jj < 5; ++jj) {
    int o = q * 5 + jj;
    float a = 0.f;
#pragma unroll
    for (int j = 0; j < 20; ++j) a = fmaf(vf[j], Lw_l[o * 20 + j], a);
    yo[jj] = a; s1 += a; s2 += a * a;
  }
#pragma unroll
  for (int off = 32; off > 0; off >>= 1) {
    s1 += __shfl_down(s1, off); s2 += __shfl_down(s2, off);
  }
  if (b == 0) { redA[q] = s1; redB[q] = s2; }
  __syncthreads();
  if (t == 0) {
    float S1 = redA[0] + redA[1] + redA[2] + redA[3];
    float S2 = redB[0] + redB[1] + redB[2] + redB[3];
    float mu = S1 * (1.f / 1280.f);
    float var = S2 * (1.f / 1280.f) - mu * mu;
    if (var < 0.f) var = 0.f;
    stats[0] = mu; stats[1] = var;
  }
  __syncthreads();
  float mu = stats[0], var = stats[1];
  float scale = gam[p] / sqrtf(var + 1e-5f);
  float shift = bet[p] - mu * scale;
#pragma unroll
  for (int jj = 0; jj < 5; ++jj) {
    int o = q * 5 + jj;
    yout[(p * 20 + o) * 64 + b] = fmaf(yo[jj], scale, shift);   // coalesced over b
  }
}

// ---------------- k_mbuild (R6-proven): materialize 64 transfer matrices once ----------------
__global__ __launch_bounds__(256)
void k_mbuild(const float* __restrict__ yn3, const float* __restrict__ coresF,
              float* __restrict__ Mmat) {
  __shared__ float ybn[64][20];
  const int s = blockIdx.x >> 2, bq = blockIdx.x & 3;
  const int t = threadIdx.x;
  for (int i = t; i < 1280; i += 256) ybn[i & 63][i >> 6] = yn3[(size_t)s * 1280 + i];
  __syncthreads();
  const float* cfp = coresF + (size_t)s * 16000;    // [40][400]
  for (int e = t; e < 400; e += 256) {
    float dlt[20]; float hsum = 0.f;
#pragma unroll
    for (int g = 0; g < 20; ++g) {
      float lo = cfp[g * 400 + e], hi = cfp[(g + 20) * 400 + e];
      dlt[g] = lo - hi; hsum += hi;
    }
    for (int bb = bq * 16; bb < bq * 16 + 16; ++bb) {
      const float4* yb = (const float4*)ybn[bb];    // uniform addr -> LDS broadcast
      float yy[20];
      *(float4*)&yy[0]  = yb[0]; *(float4*)&yy[4]  = yb[1];
      *(float4*)&yy[8]  = yb[2]; *(float4*)&yy[12] = yb[3];
      *(float4*)&yy[16] = yb[4];
      float a = hsum;
#pragma unroll
      for (int g = 0; g < 20; ++g) a = fmaf(yy[g], dlt[g], a);
      Mmat[((size_t)s * 64 + bb) * 400 + e] = a;    // lanes contiguous in e
    }
  }
}

// ---------------- k_fin (R6-proven): 8 wave-autonomous chunk folds + sequential combine ----------------
__global__ __launch_bounds__(512)
void k_fin(const float* __restrict__ Mmat, const float* __restrict__ alphaF,
           const float* __restrict__ labelF, const float* __restrict__ omegaF,
           float* __restrict__ out) {
  const int bb = blockIdx.x, t = threadIdx.x;
  const int w = t >> 6, l = t & 63;
  __shared__ float Pw[8][2][400];    // per-wave running product (ping-pong)
  __shared__ float Mw[8][400];       // per-wave M staging (reused as combine T)
  __shared__ float chunkP[8][400];
  __shared__ float LwF[200];
  __shared__ float va[20];

  if (t < 200) {
    int o = t / 20, j = t % 20;
    float a = 0.f;
#pragma unroll
    for (int k = 0; k < 20; ++k) a = fmaf(labelF[o * 400 + j * 20 + k], omegaF[k], a);
    LwF[t] = a;
  }

  // ---- wave w: chunk c = w, sites 8w .. 8w+7 ----
  float pre[7];
  {
    const size_t b0 = ((size_t)(w * 8) * 64 + bb) * 400;
#pragma unroll
    for (int it = 0; it < 7; ++it) {
      int e = l + 64 * it;
      pre[it] = (e < 400) ? Mmat[b0 + e] : 0.f;
    }
#pragma unroll
    for (int it = 0; it < 7; ++it) {
      int e = l + 64 * it;
      if (e < 400) Pw[w][0][e] = pre[it];
    }
  }
  int cur = 0;
  for (int ls = 1; ls < 8; ++ls) {
    const size_t mb = ((size_t)(w * 8 + ls) * 64 + bb) * 400;
#pragma unroll
    for (int it = 0; it < 7; ++it) {
      int e = l + 64 * it;
      if (e < 400) pre[it] = Mmat[mb + e];
    }
#pragma unroll
    for (int it = 0; it < 7; ++it) {
      int e = l + 64 * it;
      if (e < 400) Mw[w][e] = pre[it];
    }
    wave_lgkm0();
    // P' = P * M  (col-cached: 60 active lanes; lane = ii*20 + j owns rows i = ii,ii+3,..)
    if (l < 60) {
      const int j = l % 20, ii = l / 20;
      float mc[20];
#pragma unroll
      for (int k = 0; k < 20; ++k) mc[k] = Mw[w][k * 20 + j];
      for (int i = ii; i < 20; i += 3) {
        float a = 0.f;
#pragma unroll
        for (int k = 0; k < 20; ++k) a = fmaf(Pw[w][cur][i * 20 + k], mc[k], a);
        Pw[w][cur ^ 1][i * 20 + j] = a;
      }
    }
    wave_lgkm0();
    cur ^= 1;
  }
#pragma unroll
  for (int it = 0; it < 7; ++it) {
    int e = l + 64 * it;
    if (e < 400) chunkP[w][e] = Pw[w][cur][e];
  }
  __syncthreads();

  // ---- sequential combine T = ((C0*C1)*C2)... (proven association) ----
  float* T0 = &Mw[0][0];
  float* T1 = &Mw[1][0];
  if (t < 400) T0[t] = chunkP[0][t];
  __syncthreads();
  float* Tc = T0; float* Tn = T1;
  for (int c = 1; c < 8; ++c) {
    if (t < 400) {
      int i = t / 20, j = t - (t / 20) * 20;
      float a = 0.f;
#pragma unroll
      for (int k = 0; k < 20; ++k) a = fmaf(Tc[i * 20 + k], chunkP[c][k * 20 + j], a);
      Tn[t] = a;
    }
    __syncthreads();
    float* tmp = Tc; Tc = Tn; Tn = tmp;
  }
  if (t < 20) {
    float a = 0.f;
#pragma unroll
    for (int i = 0; i < 20; ++i) a = fmaf(alphaF[i], Tc[i * 20 + t], a);
    va[t] = a;
  }
  __syncthreads();
  if (t < 10) {
    float a = 0.f;
#pragma unroll
    for (int j = 0; j < 20; ++j) a = fmaf(va[j], LwF[t * 20 + j], a);
    out[bb * 10 + t] = a;
  }
}

extern "C" void kernel_launch(void* const* d_in, const int* in_sizes, int n_in,
                              void* d_out, int out_size, void* d_ws, size_t ws_size,
                              hipStream_t stream) {
  const float* x      = (const float*)d_in[0];
  const float* cores1 = (const float*)d_in[1];
  const float* label1 = (const float*)d_in[2];
  const float* alpha1 = (const float*)d_in[3];
  const float* omega1 = (const float*)d_in[4];
  const float* g1     = (const float*)d_in[5];
  const float* b1     = (const float*)d_in[6];
  const float* cores2 = (const float*)d_in[7];
  const float* label2 = (const float*)d_in[8];
  const float* alpha2 = (const float*)d_in[9];
  const float* omega2 = (const float*)d_in[10];
  const float* g2     = (const float*)d_in[11];
  const float* b2     = (const float*)d_in[12];
  const float* cores3 = (const float*)d_in[13];
  const float* label3 = (const float*)d_in[14];
  const float* alpha3 = (const float*)d_in[15];
  const float* omega3 = (const float*)d_in[16];
  const float* g3     = (const float*)d_in[17];
  const float* b3     = (const float*)d_in[18];
  const float* coresF = (const float*)d_in[19];
  const float* labelF = (const float*)d_in[20];
  const float* alphaF = (const float*)d_in[21];
  const float* omegaF = (const float*)d_in[22];

  float* ws   = (float*)d_ws;
  float* yn1  = ws;               // 1,310,720 f
  float* yn2  = yn1 + 1310720;    //   327,680 f
  float* yn3  = yn2 + 327680;     //    81,920 f
  float* Mmat = yn3 + 81920;      // 1,638,400 f (64 sites x 64 b x 400)
  float* out  = (float*)d_out;

  // dynamic LDS: u4(S*1024) + vls(9216) + Lw(1600) + red/stats(48) + CS(PH*6720)
  const size_t SM1 = 3 * 1024 + 9216 + 1600 + 48 + 3 * 6720;    // 34,096 B
  const size_t SM2 = 20 * 1024 + 9216 + 1600 + 48 + 10 * 6720;  // 98,544 B

  k_mps<1><<<1024, 256, SM1, stream>>>(x, nullptr, cores1, alpha1, label1, omega1,
                                       g1, b1, yn1);
  k_mps<2><<<256, 256, SM2, stream>>>(nullptr, yn1, cores2, alpha2, label2, omega2,
                                      g2, b2, yn2);
  k_mps<3><<<64, 256, SM2, stream>>>(nullptr, yn2, cores3, alpha3, label3, omega3,
                                     g3, b3, yn3);
  k_mbuild<<<256, 256, 0, stream>>>(yn3, coresF, Mmat);
  k_fin<<<64, 512, 0, stream>>>(Mmat, alphaF, labelF, omegaF, out);
}

// Round 10
// 248.076 us; speedup vs baseline: 1.0956x; 1.0956x over previous
//
#include <hip/hip_runtime.h>
#include <hip/hip_bf16.h>

typedef __attribute__((ext_vector_type(4))) float f32x4;
typedef __attribute__((ext_vector_type(8))) short s16x8;

static __device__ __forceinline__ short f2bf(float x) {
  __hip_bfloat16 h = __float2bfloat16(x);
  return *reinterpret_cast<short*>(&h);
}

// Intra-wave LDS fence (used by k_fin only).
static __device__ __forceinline__ void wave_lgkm0() {
  asm volatile("s_waitcnt lgkmcnt(0)" ::: "memory");
  __builtin_amdgcn_sched_barrier(0);
}

// ---------------- MFMA MPS stages 1..3 with fused BatchNorm + inline Lw ----------------
// R6-PROVEN (254.17us). Block = patch p, 256 thr = 4 waves. v in registers as the
// MFMA C-operand; per-site C' double-buffer, prefetch distance 3, one barrier/site.
// STAGE==3 fuses the final-MPS transfer-matrix build into the epilogue (Mmat[p] is
// block-local; kills the k_mbuild dispatch).
template<int STAGE>
__global__ __launch_bounds__(256)
void k_mps(const float* __restrict__ xsrc, const float* __restrict__ ysrc,
           const float* __restrict__ cores, const float* __restrict__ alpha,
           const float* __restrict__ label, const float* __restrict__ omega,
           const float* __restrict__ gam, const float* __restrict__ bet,
           float* __restrict__ yout, const float* __restrict__ coresF,
           float* __restrict__ Mmat) {
  constexpr int S = (STAGE == 1) ? 3 : 20;
  __shared__ __align__(16) float u4[S][64][4];      // [site][b][g]
  __shared__ __align__(16) short Cl[2][32][168];    // [buf][n-row][k'], pad 168
  __shared__ __align__(16) float vls[64][36];       // [b][i], cols 20..35 zero
  __shared__ float Lw_l[400];
  __shared__ float redA[4], redB[4], stats[2];

  const int p = blockIdx.x, t = threadIdx.x;
  const int b = t & 63, q = t >> 6;
  const int m = b & 15, quad = b >> 4;
  const int bl = q * 16 + m;

  const bool two = (t < 144);                        // 400 = 256 + 144
  const float* cbase = cores + (size_t)p * S * 3200;

  // ---- issue site-0 raw core loads (in flight during all init) ----
  float p0A[8], p0B[8], p1A[8], p1B[8];
#pragma unroll
  for (int g = 0; g < 8; ++g) p0A[g] = cbase[g * 400 + t];
  if (two) {
#pragma unroll
    for (int g = 0; g < 8; ++g) p0B[g] = cbase[g * 400 + 256 + t];
  }

  // ---- Lw[o][j] = sum_k label[o][j][k]*omega[k] ----
  for (int e = t; e < 400; e += 256) {
    int o = e / 20, j = e % 20;
    float a = 0.f;
#pragma unroll
    for (int k = 0; k < 20; ++k) a = fmaf(label[o * 400 + j * 20 + k], omega[k], a);
    Lw_l[e] = a;
  }

  // ---- zero FULL C' (both buffers); init v = alpha (cols >=20 zero) ----
  {
    int* cz = (int*)&Cl[0][0][0];                    // 2*32*168 shorts = 5376 ints
    for (int i = t; i < 5376; i += 256) cz[i] = 0;
    for (int i = t; i < 64 * 36; i += 256) {
      int col = i % 36;
      vls[i / 36][col] = (col < 20) ? alpha[col] : 0.f;
    }
  }

  // ---- v in registers, MFMA D-layout ----
  float vr0[4], vr1[4];
  {
    float a0 = alpha[m];
    float a1 = (m < 4) ? alpha[m + 16] : 0.f;
#pragma unroll
    for (int r = 0; r < 4; ++r) { vr0[r] = a0; vr1[r] = a1; }
  }

  // ---- gather u (faithful raw-reshape unfold permutation); u4[k][b][g=q] ----
  for (int k = 0; k < S; ++k) {
    float val;
    if (STAGE == 1) {
      int L = q * 3072 + p * 3 + k;           // [4,1024,3] flat
      int c = L >> 12, r = L & 4095;          // dims [3,32,32,2,2]
      int hh = 2 * (r >> 7) + ((r >> 1) & 1);
      int ww = 2 * ((r >> 2) & 31) + (r & 1);
      val = xsrc[(b * 3 + c) * 4096 + hh * 64 + ww];
    } else if (STAGE == 2) {
      int L = q * 5120 + p * 20 + k;          // [4,256,20] flat
      int c = L >> 10, r = L & 1023;          // dims [20,16,16,2,2]
      int f = c * 1024 + (2 * (r >> 6) + ((r >> 1) & 1)) * 32
                        + (2 * ((r >> 2) & 15) + (r & 1));
      val = ysrc[f * 64 + b];                 // b innermost -> coalesced
    } else {
      int L = q * 1280 + p * 20 + k;          // [4,64,20] flat
      int c = L >> 8, r = L & 255;            // dims [20,8,8,2,2]
      int f = c * 256 + (2 * (r >> 5) + ((r >> 1) & 1)) * 16
                       + (2 * ((r >> 2) & 7) + (r & 1));
      val = ysrc[f * 64 + b];
    }
    u4[k][b][q] = val;
  }

  // C'-entry writer: entry e=(i*20+j) from raw feature regs r[0..8)
  auto writeC = [&](int buf, int e, const float* r) {
    int i = e / 20, j = e % 20;
    Cl[buf][j][      i] = f2bf(r[0] - r[4]);
    Cl[buf][j][ 32 + i] = f2bf(r[1] - r[5]);
    Cl[buf][j][ 64 + i] = f2bf(r[2] - r[6]);
    Cl[buf][j][ 96 + i] = f2bf(r[3] - r[7]);
    float cs = r[4] + r[5] + r[6] + r[7];
    if (i == j) cs -= 1.f;
    Cl[buf][j][128 + i] = f2bf(cs);
  };
  auto loadSite = [&](int s, float (&rA)[8], float (&rB)[8]) {
    const float* cs = cbase + (size_t)s * 3200;
#pragma unroll
    for (int g = 0; g < 8; ++g) rA[g] = cs[g * 400 + t];
    if (two) {
#pragma unroll
      for (int g = 0; g < 8; ++g) rB[g] = cs[g * 400 + 256 + t];
    }
  };

  // build C'[0] from site-0 regs; then fill the pipeline: s1 -> P0, s2 -> P1
  writeC(0, t, p0A);
  if (two) writeC(0, t + 256, p0B);
  if (S > 1) loadSite(1, p0A, p0B);
  if (S > 2) loadSite(2, p1A, p1B);
  __syncthreads();

  // ---- one site step; cur/regset passed statically ----
  auto site_step = [&](int s, int cur, float (&rA)[8], float (&rB)[8]) {
    const float4 uu = *(const float4*)&u4[s][bl][0];
    const float4 va = *(const float4*)&vls[bl][quad * 8];
    const float4 vb = *(const float4*)&vls[bl][quad * 8 + 4];
    const float vv[8] = {va.x, va.y, va.z, va.w, vb.x, vb.y, vb.z, vb.w};
    const float um[5] = {uu.x, uu.y, uu.z, uu.w, 1.f};

    f32x4 acc0, acc1;
#pragma unroll
    for (int r = 0; r < 4; ++r) { acc0[r] = vr0[r]; acc1[r] = vr1[r]; }
#pragma unroll
    for (int kt = 0; kt < 5; ++kt) {
      s16x8 aF;
#pragma unroll
      for (int j2 = 0; j2 < 8; ++j2) aF[j2] = f2bf(vv[j2] * um[kt]);
      const s16x8 bF0 = *(const s16x8*)&Cl[cur][m][kt * 32 + quad * 8];
      const s16x8 bF1 = *(const s16x8*)&Cl[cur][m + 16][kt * 32 + quad * 8];
      acc0 = __builtin_amdgcn_mfma_f32_16x16x32_bf16(aF, bF0, acc0, 0, 0, 0);
      acc1 = __builtin_amdgcn_mfma_f32_16x16x32_bf16(aF, bF1, acc1, 0, 0, 0);
    }

    // stage next site's C' (regs loaded 2 sites ago); refill this regset for s+3
    if (s + 1 < S) {
      writeC(cur ^ 1, t, rA);
      if (two) writeC(cur ^ 1, t + 256, rB);
      if (s + 3 < S) loadSite(s + 3, rA, rB);
    }

    // v lives in acc; publish D->A relayout for next site's A-read
#pragma unroll
    for (int r = 0; r < 4; ++r) { vr0[r] = acc0[r]; vr1[r] = acc1[r]; }
#pragma unroll
    for (int r = 0; r < 4; ++r) vls[q * 16 + quad * 4 + r][m] = acc0[r];
    if (m < 4) {
#pragma unroll
      for (int r = 0; r < 4; ++r) vls[q * 16 + quad * 4 + r][m + 16] = acc1[r];
    }
    __syncthreads();   // the only per-site barrier
  };

  for (int s = 0; s < S; s += 2) {
    site_step(s, 0, p0A, p0B);
    if (s + 1 < S) site_step(s + 1, 1, p1A, p1B);
  }

  // ---- epilogue: Lw projection + fused BatchNorm (stats over 64b x 20o) ----
  float vf[20];
  {
    const float4 v0 = *(const float4*)&vls[b][0];
    const float4 v1 = *(const float4*)&vls[b][4];
    const float4 v2 = *(const float4*)&vls[b][8];
    const float4 v3 = *(const float4*)&vls[b][12];
    const float4 v4 = *(const float4*)&vls[b][16];
    vf[0]=v0.x; vf[1]=v0.y; vf[2]=v0.z; vf[3]=v0.w;
    vf[4]=v1.x; vf[5]=v1.y; vf[6]=v1.z; vf[7]=v1.w;
    vf[8]=v2.x; vf[9]=v2.y; vf[10]=v2.z; vf[11]=v2.w;
    vf[12]=v3.x; vf[13]=v3.y; vf[14]=v3.z; vf[15]=v3.w;
    vf[16]=v4.x; vf[17]=v4.y; vf[18]=v4.z; vf[19]=v4.w;
  }
  float yo[5];
  float s1 = 0.f, s2 = 0.f;
#pragma unroll
  for (int jj = 0; jj < 5; ++jj) {
    int o = q * 5 + jj;
    float a = 0.f;
#pragma unroll
    for (int j = 0; j < 20; ++j) a = fmaf(vf[j], Lw_l[o * 20 + j], a);
    yo[jj] = a; s1 += a; s2 += a * a;
  }
#pragma unroll
  for (int off = 32; off > 0; off >>= 1) {
    s1 += __shfl_down(s1, off); s2 += __shfl_down(s2, off);
  }
  if (b == 0) { redA[q] = s1; redB[q] = s2; }
  __syncthreads();
  if (t == 0) {
    float S1 = redA[0] + redA[1] + redA[2] + redA[3];
    float S2 = redB[0] + redB[1] + redB[2] + redB[3];
    float mu = S1 * (1.f / 1280.f);
    float var = S2 * (1.f / 1280.f) - mu * mu;
    if (var < 0.f) var = 0.f;
    stats[0] = mu; stats[1] = var;
  }
  __syncthreads();
  float mu = stats[0], var = stats[1];
  float scale = gam[p] / sqrtf(var + 1e-5f);
  float shift = bet[p] - mu * scale;

  if constexpr (STAGE != 3) {
#pragma unroll
    for (int jj = 0; jj < 5; ++jj) {
      int o = q * 5 + jj;
      yout[(p * 20 + o) * 64 + b] = fmaf(yo[jj], scale, shift);   // coalesced over b
    }
  } else {
    // ---- fused transfer-matrix build (Mmat[p] is block-local; R6-proven) ----
    // vf reads completed before the stats barriers -> safe to overwrite vls.
#pragma unroll
    for (int jj = 0; jj < 5; ++jj) {
      int o = q * 5 + jj;
      vls[b][o] = fmaf(yo[jj], scale, shift);     // post-BN y[b][o], disjoint writers
    }
    __syncthreads();
    const float* cfp = coresF + (size_t)p * 16000;          // [40][400] for site p
    for (int e = t; e < 400; e += 256) {
      float dlt[20]; float hsum = 0.f;
#pragma unroll
      for (int g = 0; g < 20; ++g) {
        float lo = cfp[g * 400 + e], hi = cfp[(g + 20) * 400 + e];
        dlt[g] = lo - hi; hsum += hi;
      }
      for (int bb = 0; bb < 64; ++bb) {
        const float4* yb = (const float4*)&vls[bb][0];       // uniform -> LDS broadcast
        float yy[20];
        *(float4*)&yy[0]  = yb[0]; *(float4*)&yy[4]  = yb[1];
        *(float4*)&yy[8]  = yb[2]; *(float4*)&yy[12] = yb[3];
        *(float4*)&yy[16] = yb[4];
        float a = hsum;
#pragma unroll
        for (int g = 0; g < 20; ++g) a = fmaf(yy[g], dlt[g], a);
        Mmat[((size_t)p * 64 + bb) * 400 + e] = a;           // lanes contiguous in e
      }
    }
  }
}

// ---------------- k_fin (R7-proven): 8 wave-autonomous chunk folds + sequential combine ----------------
__global__ __launch_bounds__(512)
void k_fin(const float* __restrict__ Mmat, const float* __restrict__ alphaF,
           const float* __restrict__ labelF, const float* __restrict__ omegaF,
           float* __restrict__ out) {
  const int bb = blockIdx.x, t = threadIdx.x;
  const int w = t >> 6, l = t & 63;
  __shared__ float Pw[8][2][400];    // per-wave running product (ping-pong)
  __shared__ float Mw[8][400];       // per-wave M staging (reused as combine T)
  __shared__ float chunkP[8][400];
  __shared__ float LwF[200];
  __shared__ float va[20];

  if (t < 200) {
    int o = t / 20, j = t % 20;
    float a = 0.f;
#pragma unroll
    for (int k = 0; k < 20; ++k) a = fmaf(labelF[o * 400 + j * 20 + k], omegaF[k], a);
    LwF[t] = a;
  }

  // ---- wave w: chunk c = w, sites 8w .. 8w+7 ----
  float pre[7];
  {
    const size_t b0 = ((size_t)(w * 8) * 64 + bb) * 400;
#pragma unroll
    for (int it = 0; it < 7; ++it) {
      int e = l + 64 * it;
      pre[it] = (e < 400) ? Mmat[b0 + e] : 0.f;
    }
#pragma unroll
    for (int it = 0; it < 7; ++it) {
      int e = l + 64 * it;
      if (e < 400) Pw[w][0][e] = pre[it];
    }
  }
  int cur = 0;
  for (int ls = 1; ls < 8; ++ls) {
    const size_t mb = ((size_t)(w * 8 + ls) * 64 + bb) * 400;
#pragma unroll
    for (int it = 0; it < 7; ++it) {
      int e = l + 64 * it;
      if (e < 400) pre[it] = Mmat[mb + e];
    }
#pragma unroll
    for (int it = 0; it < 7; ++it) {
      int e = l + 64 * it;
      if (e < 400) Mw[w][e] = pre[it];
    }
    wave_lgkm0();
    // P' = P * M  (col-cached: 60 active lanes; lane = ii*20 + j owns rows i = ii,ii+3,..)
    if (l < 60) {
      const int j = l % 20, ii = l / 20;
      float mc[20];
#pragma unroll
      for (int k = 0; k < 20; ++k) mc[k] = Mw[w][k * 20 + j];
      for (int i = ii; i < 20; i += 3) {
        float a = 0.f;
#pragma unroll
        for (int k = 0; k < 20; ++k) a = fmaf(Pw[w][cur][i * 20 + k], mc[k], a);
        Pw[w][cur ^ 1][i * 20 + j] = a;
      }
    }
    wave_lgkm0();
    cur ^= 1;
  }
#pragma unroll
  for (int it = 0; it < 7; ++it) {
    int e = l + 64 * it;
    if (e < 400) chunkP[w][e] = Pw[w][cur][e];
  }
  __syncthreads();

  // ---- sequential combine T = ((C0*C1)*C2)... (proven association) ----
  float* T0 = &Mw[0][0];
  float* T1 = &Mw[1][0];
  if (t < 400) T0[t] = chunkP[0][t];
  __syncthreads();
  float* Tc = T0; float* Tn = T1;
  for (int c = 1; c < 8; ++c) {
    if (t < 400) {
      int i = t / 20, j = t - (t / 20) * 20;
      float a = 0.f;
#pragma unroll
      for (int k = 0; k < 20; ++k) a = fmaf(Tc[i * 20 + k], chunkP[c][k * 20 + j], a);
      Tn[t] = a;
    }
    __syncthreads();
    float* tmp = Tc; Tc = Tn; Tn = tmp;
  }
  if (t < 20) {
    float a = 0.f;
#pragma unroll
    for (int i = 0; i < 20; ++i) a = fmaf(alphaF[i], Tc[i * 20 + t], a);
    va[t] = a;
  }
  __syncthreads();
  if (t < 10) {
    float a = 0.f;
#pragma unroll
    for (int j = 0; j < 20; ++j) a = fmaf(va[j], LwF[t * 20 + j], a);
    out[bb * 10 + t] = a;
  }
}

extern "C" void kernel_launch(void* const* d_in, const int* in_sizes, int n_in,
                              void* d_out, int out_size, void* d_ws, size_t ws_size,
                              hipStream_t stream) {
  const float* x      = (const float*)d_in[0];
  const float* cores1 = (const float*)d_in[1];
  const float* label1 = (const float*)d_in[2];
  const float* alpha1 = (const float*)d_in[3];
  const float* omega1 = (const float*)d_in[4];
  const float* g1     = (const float*)d_in[5];
  const float* b1     = (const float*)d_in[6];
  const float* cores2 = (const float*)d_in[7];
  const float* label2 = (const float*)d_in[8];
  const float* alpha2 = (const float*)d_in[9];
  const float* omega2 = (const float*)d_in[10];
  const float* g2     = (const float*)d_in[11];
  const float* b2     = (const float*)d_in[12];
  const float* cores3 = (const float*)d_in[13];
  const float* label3 = (const float*)d_in[14];
  const float* alpha3 = (const float*)d_in[15];
  const float* omega3 = (const float*)d_in[16];
  const float* g3     = (const float*)d_in[17];
  const float* b3     = (const float*)d_in[18];
  const float* coresF = (const float*)d_in[19];
  const float* labelF = (const float*)d_in[20];
  const float* alphaF = (const float*)d_in[21];
  const float* omegaF = (const float*)d_in[22];

  float* ws   = (float*)d_ws;
  float* yn1  = ws;               // 1,310,720 f
  float* yn2  = yn1 + 1310720;    //   327,680 f
  float* Mmat = yn2 + 327680;     // 1,638,400 f (64 sites x 64 b x 400)
  float* out  = (float*)d_out;

  k_mps<1><<<1024, 256, 0, stream>>>(x, nullptr, cores1, alpha1, label1, omega1,
                                     g1, b1, yn1, nullptr, nullptr);
  k_mps<2><<<256, 256, 0, stream>>>(nullptr, yn1, cores2, alpha2, label2, omega2,
                                    g2, b2, yn2, nullptr, nullptr);
  k_mps<3><<<64, 256, 0, stream>>>(nullptr, yn2, cores3, alpha3, label3, omega3,
                                   g3, b3, nullptr, coresF, Mmat);
  k_fin<<<64, 512, 0, stream>>>(Mmat, alphaF, labelF, omegaF, out);
}